// Round 1
// baseline (227.631 us; speedup 1.0000x reference)
//
#include <hip/hip_runtime.h>
#include <stdint.h>

// Problem constants (fixed by reference setup_inputs)
#define CIN   256
#define COUT  256
#define Hdim  56
#define Wdim  56
#define HW    3136        // 56*56
#define BATCH 32
#define NPIX  100352      // 32*3136
#define KREP  589824      // 256*256*9, stride between weight replicas
#define TAPS  9
#define WORDS 8           // 8 x uint32 = 256 channel bits

// ws layout (bytes)
#define OFF_WPACK 0         // 256*72*4   = 73728
#define OFF_CORR  73728     // 9*256*4    = 9216
#define OFF_SA    82944     // 256*4      = 1024
#define OFF_XBITS 84224     // 100352*8*4 = 3211264   (16B aligned)

// ---------------------------------------------------------------------------
// P1: build real_w = sum_k RV[k]*W[k], pack sign bits per (co, tap, word),
//     compute sa[co] = mean|real_w| * alpha[co], and the border-correction
//     table corr[pattern][co] = sum of popc(wbits) over invalid taps.
// One block per co, 256 threads.
// ---------------------------------------------------------------------------
__global__ __launch_bounds__(256) void prep_w_kernel(
    const float* __restrict__ wts, const float* __restrict__ RV,
    const float* __restrict__ alpha, uint32_t* __restrict__ wpack,
    uint32_t* __restrict__ corr, float* __restrict__ sa)
{
    __shared__ uint32_t bits[TAPS * WORDS];   // 72 words
    __shared__ float    red[256];
    __shared__ int      pcw[TAPS];

    const int co = blockIdx.x;
    const int t  = threadIdx.x;

    if (t < TAPS * WORDS) bits[t] = 0u;
    __syncthreads();

    const float r0 = RV[0], r1 = RV[1], r2 = RV[2], r3 = RV[3];
    const float* base = wts + (size_t)co * 2304;

    float acc = 0.f;
#pragma unroll
    for (int j = 0; j < 9; ++j) {
        const int e = j * 256 + t;              // 0..2303, e = ci*9 + tap
        const float w0 = base[e];
        const float w1 = base[e + KREP];
        const float w2 = base[e + 2 * KREP];
        const float w3 = base[e + 3 * KREP];
        const float rw = r0 * w0 + r1 * w1 + r2 * w2 + r3 * w3;
        acc += fabsf(rw);
        const int ci  = e / 9;
        const int tap = e - ci * 9;
        if (rw < 0.f)
            atomicOr(&bits[tap * WORDS + (ci >> 5)], 1u << (ci & 31));
    }
    red[t] = acc;
    __syncthreads();

    for (int s = 128; s > 0; s >>= 1) {
        if (t < s) red[t] += red[t + s];
        __syncthreads();
    }

    if (t == 0) {
        const float scale = red[0] * (1.0f / 2304.0f);
        sa[co] = scale * alpha[co];
    }
    if (t < TAPS * WORDS) wpack[co * 72 + t] = bits[t];
    if (t < TAPS) {
        int s = 0;
#pragma unroll
        for (int wd = 0; wd < WORDS; ++wd) s += __popc(bits[t * WORDS + wd]);
        pcw[t] = s;
    }
    __syncthreads();
    if (t < TAPS) {
        const int vp = t / 3, hp = t % 3;   // pattern id: vp*3+hp
        int c = 0;
#pragma unroll
        for (int kh = 0; kh < 3; ++kh)
#pragma unroll
            for (int kw = 0; kw < 3; ++kw) {
                const bool inv = (vp == 0 && kh == 0) || (vp == 2 && kh == 2) ||
                                 (hp == 0 && kw == 0) || (hp == 2 && kw == 2);
                if (inv) c += pcw[kh * 3 + kw];
            }
        corr[t * 256 + co] = (uint32_t)c;
    }
}

// ---------------------------------------------------------------------------
// P2: binarize+pack x: xbits[pixel][8 words], bit ci = signbit(x[b,ci,h,w]).
// One thread per pixel; per-iteration loads are wave-coalesced (consecutive hw).
// ---------------------------------------------------------------------------
__global__ __launch_bounds__(256) void pack_x_kernel(
    const float* __restrict__ x, uint32_t* __restrict__ xbits)
{
    const int p  = blockIdx.x * 256 + threadIdx.x;   // pixel id < NPIX
    const int b  = p / HW;
    const int hw = p - b * HW;
    const float* xp = x + (size_t)b * CIN * HW + hw;

    uint32_t wv[WORDS];
#pragma unroll
    for (int j = 0; j < WORDS; ++j) {
        uint32_t m = 0;
#pragma unroll
        for (int bit = 0; bit < 32; ++bit) {
            const float v = xp[(size_t)(j * 32 + bit) * HW];
            m |= (__float_as_uint(v) >> 31) << bit;   // sign bit
        }
        wv[j] = m;
    }
    uint4* dst = (uint4*)(xbits + (size_t)p * WORDS);
    dst[0] = make_uint4(wv[0], wv[1], wv[2], wv[3]);
    dst[1] = make_uint4(wv[4], wv[5], wv[6], wv[7]);
}

// ---------------------------------------------------------------------------
// C: XNOR-popcount conv. Grid = 392 pixel-blocks x 2 co-chunks (flat 784).
// Each thread owns one pixel, computes 128 co of its chunk.
// W bits for the chunk staged in LDS; reads are wave-uniform (broadcast).
// ---------------------------------------------------------------------------
__global__ __launch_bounds__(256) void conv_xnor_kernel(
    const uint32_t* __restrict__ xbits, const uint32_t* __restrict__ wpack,
    const uint32_t* __restrict__ corr_g, const float* __restrict__ sa_g,
    float* __restrict__ out)
{
    __shared__ __align__(16) uint32_t wch[128 * 72];   // 36864 B
    __shared__ uint32_t corr_s[9 * 257];               // stride 257: banks split
    __shared__ float    sa_s[COUT];

    const int tid = threadIdx.x;
    const int pb  = blockIdx.x >> 1;      // pixel block
    const int ch  = blockIdx.x & 1;       // co chunk (0/1)

    const int p  = pb * 256 + tid;
    const int b  = p / HW;
    const int hw = p - b * HW;
    const int h  = hw / Wdim;
    const int w  = hw - h * Wdim;

    // stage corr + sa
#pragma unroll
    for (int j = 0; j < 9; ++j) corr_s[j * 257 + tid] = corr_g[j * 256 + tid];
    sa_s[tid] = sa_g[tid];

    // stage this chunk's weight bits: 9216 words, 36 per thread
    {
        const uint4* src = (const uint4*)(wpack + ch * 128 * 72);
        uint4* dst = (uint4*)wch;
#pragma unroll
        for (int j = 0; j < 9; ++j) dst[j * 256 + tid] = src[j * 256 + tid];
    }

    // border pattern
    const int vp  = (h == 0) ? 0 : ((h == Hdim - 1) ? 2 : 1);
    const int hp  = (w == 0) ? 0 : ((w == Wdim - 1) ? 2 : 1);
    const int pat = vp * 3 + hp;
    const int ntap  = ((vp == 1) ? 3 : 2) * ((hp == 1) ? 3 : 2);
    const int basei = 256 * ntap;

    // load x bits for the 9 taps (invalid taps -> 0)
    uint32_t xq[72];
#pragma unroll
    for (int kh = 0; kh < 3; ++kh)
#pragma unroll
        for (int kw = 0; kw < 3; ++kw) {
            const int t  = kh * 3 + kw;
            const int hh = h + kh - 1, ww = w + kw - 1;
            if (hh >= 0 && hh < Hdim && ww >= 0 && ww < Wdim) {
                const uint4* src =
                    (const uint4*)(xbits + (size_t)(b * HW + hh * Wdim + ww) * WORDS);
                const uint4 a = src[0], c = src[1];
                xq[t * 8 + 0] = a.x; xq[t * 8 + 1] = a.y;
                xq[t * 8 + 2] = a.z; xq[t * 8 + 3] = a.w;
                xq[t * 8 + 4] = c.x; xq[t * 8 + 5] = c.y;
                xq[t * 8 + 6] = c.z; xq[t * 8 + 7] = c.w;
            } else {
#pragma unroll
                for (int j = 0; j < 8; ++j) xq[t * 8 + j] = 0u;
            }
        }

    __syncthreads();

    float* outp = out + (size_t)b * COUT * HW + hw;

#pragma unroll 2
    for (int col = 0; col < 128; ++col) {
        const int co = ch * 128 + col;
        const uint4* wp4 = (const uint4*)&wch[col * 72];
        int mm = 0;
#pragma unroll
        for (int q = 0; q < 18; ++q) {
            const uint4 wv = wp4[q];
            mm += __popc(xq[q * 4 + 0] ^ wv.x);
            mm += __popc(xq[q * 4 + 1] ^ wv.y);
            mm += __popc(xq[q * 4 + 2] ^ wv.z);
            mm += __popc(xq[q * 4 + 3] ^ wv.w);
        }
        const int corr = (int)corr_s[pat * 257 + co];
        const float val = sa_s[co] * (float)(basei - 2 * mm + 2 * corr);
        outp[(size_t)co * HW] = val;
    }
}

extern "C" void kernel_launch(void* const* d_in, const int* in_sizes, int n_in,
                              void* d_out, int out_size, void* d_ws, size_t ws_size,
                              hipStream_t stream) {
    const float* x     = (const float*)d_in[0];   // [32,256,56,56]
    const float* wts   = (const float*)d_in[1];   // [4,256,256,3,3]
    const float* RV    = (const float*)d_in[2];   // [5]
    const float* alpha = (const float*)d_in[3];   // [256,1,1]
    float* out = (float*)d_out;                   // [32,256,56,56]

    uint8_t* ws = (uint8_t*)d_ws;
    uint32_t* wpack  = (uint32_t*)(ws + OFF_WPACK);
    uint32_t* corr   = (uint32_t*)(ws + OFF_CORR);
    float*    sa     = (float*)   (ws + OFF_SA);
    uint32_t* xbits  = (uint32_t*)(ws + OFF_XBITS);

    prep_w_kernel<<<COUT, 256, 0, stream>>>(wts, RV, alpha, wpack, corr, sa);
    pack_x_kernel<<<NPIX / 256, 256, 0, stream>>>(x, xbits);
    conv_xnor_kernel<<<(NPIX / 256) * 2, 256, 0, stream>>>(xbits, wpack, corr, sa, out);
}